// Round 3
// baseline (153.652 us; speedup 1.0000x reference)
//
#include <hip/hip_runtime.h>

#define BATCH 4096
#define D_IN 1024
#define D_OUT 1024
#define N_EXPERTS 8

#define TM 64
#define TN 128
#define TK 32
#define MAX_TILES 71   // sum ceil(c_e/64) <= 64 + 7

// ws int32 region (slots)
#define WS_PERM    0       // [4096]
#define WS_STARTS  4096    // [9]
#define WS_TILE_E  4112    // [71]
#define WS_TILE_M  4200    // [71]
#define WS_NTILES  4288    // [1]

// staged bf16 regions (byte offsets into ws)
#define WS_XHI_OFF   32768
#define WS_XLO_OFF   (32768 + 8388608)
#define WS_WHI_OFF   (32768 + 2*8388608)
#define WS_WLO_OFF   (32768 + 2*8388608 + 16777216)
#define WS_NEEDED    (32768 + 2*8388608 + 2*16777216)   // 50,364,416 B

typedef __attribute__((ext_vector_type(8))) short short8;   // 8 x bf16
typedef __attribute__((ext_vector_type(4))) float f32x4;

// fp32 -> bf16 hi/lo split (truncation; lo = next 8 mantissa bits). Unchanged.
__device__ __forceinline__ void cvt8(const float4 a, const float4 b,
                                     short8& h, short8& l) {
    float f[8] = {a.x, a.y, a.z, a.w, b.x, b.y, b.z, b.w};
#pragma unroll
    for (int i = 0; i < 8; ++i) {
        const unsigned u = __float_as_uint(f[i]);
        h[i] = (short)(u >> 16);
        const float r = f[i] - __uint_as_float(u & 0xffff0000u);
        l[i] = (short)(__float_as_uint(r) >> 16);
    }
}

// ---------------------------------------------------------------------------
// Fused prep kernel:
//   block 0      : ballot-based grouping (replaces the 2x4096 same-address
//                  LDS-atomic storm that was ~45 us hiding under the top-5)
//   blocks 1..16 : meta tail writes
//   blocks 17+   : stream-convert W -> Whi/Wlo (fragment-staged order) and
//                  xs -> Xhi/Xlo (row-major). Memory-bound; hides block 0.
// ---------------------------------------------------------------------------
__global__ __launch_bounds__(256) void prep_kernel(
    const int* __restrict__ actions, const int* __restrict__ mxs,
    const float* __restrict__ xs, const float* __restrict__ W,
    int* __restrict__ ws,
    short* __restrict__ XhiP, short* __restrict__ XloP,
    short* __restrict__ WhiP, short* __restrict__ WloP,
    float* __restrict__ out, int meta_mode)
{
    const int bid = blockIdx.x;
    const int t = threadIdx.x;

    if (bid == 0) {
        // ---- grouping via ballots: 64 chunks of 64 samples ----
        __shared__ int chunkoff[64][N_EXPERTS];   // counts, then offsets
        const int lane = t & 63;
        const int wave = t >> 6;

        // pass 1: per-chunk per-expert counts
        for (int it = 0; it < 16; ++it) {
            const int c = wave * 16 + it;
            const int a = actions[c * 64 + lane];
            int myc = 0;
#pragma unroll
            for (int e = 0; e < N_EXPERTS; ++e) {
                const unsigned long long me = __ballot(a == e);
                if (lane == e) myc = (int)__popcll(me);
            }
            if (lane < N_EXPERTS) chunkoff[c][lane] = myc;
        }
        __syncthreads();

        // scan (wave 0): per-expert exclusive scan over chunks + expert bases
        if (wave == 0) {
            int cc0 = chunkoff[lane][0], cc1 = chunkoff[lane][1];
            int cc2 = chunkoff[lane][2], cc3 = chunkoff[lane][3];
            int cc4 = chunkoff[lane][4], cc5 = chunkoff[lane][5];
            int cc6 = chunkoff[lane][6], cc7 = chunkoff[lane][7];
            int tot0, tot1, tot2, tot3, tot4, tot5, tot6, tot7;
            int ex0, ex1, ex2, ex3, ex4, ex5, ex6, ex7;
#define SCAN1(CC, TOT, EX) do {                                   \
            int v = CC;                                           \
            _Pragma("unroll")                                     \
            for (int d = 1; d < 64; d <<= 1) {                    \
                const int u = __shfl_up(v, d, 64);                \
                if (lane >= d) v += u;                            \
            }                                                     \
            TOT = __shfl(v, 63, 64);                              \
            EX = v - CC;                                          \
        } while (0)
            SCAN1(cc0, tot0, ex0); SCAN1(cc1, tot1, ex1);
            SCAN1(cc2, tot2, ex2); SCAN1(cc3, tot3, ex3);
            SCAN1(cc4, tot4, ex4); SCAN1(cc5, tot5, ex5);
            SCAN1(cc6, tot6, ex6); SCAN1(cc7, tot7, ex7);
#undef SCAN1
            const int b0 = 0;
            const int b1 = b0 + tot0, b2 = b1 + tot1, b3 = b2 + tot2;
            const int b4 = b3 + tot3, b5 = b4 + tot4, b6 = b5 + tot5;
            const int b7 = b6 + tot6;
            chunkoff[lane][0] = b0 + ex0; chunkoff[lane][1] = b1 + ex1;
            chunkoff[lane][2] = b2 + ex2; chunkoff[lane][3] = b3 + ex3;
            chunkoff[lane][4] = b4 + ex4; chunkoff[lane][5] = b5 + ex5;
            chunkoff[lane][6] = b6 + ex6; chunkoff[lane][7] = b7 + ex7;
            if (lane == 0) {
                ws[WS_STARTS + 0] = b0; ws[WS_STARTS + 1] = b1;
                ws[WS_STARTS + 2] = b2; ws[WS_STARTS + 3] = b3;
                ws[WS_STARTS + 4] = b4; ws[WS_STARTS + 5] = b5;
                ws[WS_STARTS + 6] = b6; ws[WS_STARTS + 7] = b7;
                ws[WS_STARTS + 8] = BATCH;
                int nt = 0;
                int tots[8] = {tot0, tot1, tot2, tot3, tot4, tot5, tot6, tot7};
#pragma unroll
                for (int e = 0; e < N_EXPERTS; ++e)
                    for (int m0 = 0; m0 < tots[e]; m0 += TM) {
                        ws[WS_TILE_E + nt] = e;
                        ws[WS_TILE_M + nt] = m0;
                        ++nt;
                    }
                ws[WS_NTILES] = nt;
            }
        }
        __syncthreads();

        // pass 2: rank within chunk -> permutation
        for (int it = 0; it < 16; ++it) {
            const int c = wave * 16 + it;
            const int i = c * 64 + lane;
            const int a = actions[i];
            unsigned long long msel = 0;
#pragma unroll
            for (int e = 0; e < N_EXPERTS; ++e) {
                const unsigned long long me = __ballot(a == e);
                if (a == e) msel = me;
            }
            const int rank = (int)__popcll(msel & ((1ull << lane) - 1ull));
            const int pos = chunkoff[c][a] + rank;
            ws[WS_PERM + pos] = i;
        }
        return;
    }

    if (bid <= 16) {
        // ---- meta tail ----
        const int i = (bid - 1) * 256 + t;
        if (meta_mode == 2) {
            out[BATCH * D_OUT + i] = (float)mxs[i];
            long long* a64 = (long long*)(out + BATCH * D_OUT + BATCH);
            a64[i] = (long long)actions[i];
        } else if (meta_mode == 1) {
            out[BATCH * D_OUT + i] = (float)mxs[i];
            out[BATCH * D_OUT + BATCH + i] = (float)actions[i];
        }
        return;
    }

    // ---- precompute: output-linear mapping (contiguous 16B writes/lane) ----
    const int g = (bid - 17) * 256 + t;
    if (g < 1048576) {
        // W unit: staged short idx = g*8.
        // g = (((e*32+kt)*8+nt)*8 + i2)*64 + slot ; slot = j*16 + c
        const int slot = g & 63;
        const int i2   = (g >> 6) & 7;
        const int blk  = g >> 9;
        const int nt   = blk & 7;
        const int kt   = (blk >> 3) & 31;
        const int e    = blk >> 8;
        const int c    = slot & 15;
        const int j    = slot >> 4;
        const int n    = nt * 128 + i2 * 16 + c;
        const float* p = W + ((size_t)(e << 10) + n) * D_IN + kt * 32 + j * 8;
        const float4 f0 = *(const float4*)p;
        const float4 f1 = *(const float4*)(p + 4);
        short8 h, l;
        cvt8(f0, f1, h, l);
        *(short8*)(WhiP + (size_t)g * 8) = h;
        *(short8*)(WloP + (size_t)g * 8) = l;
    } else {
        const int g2 = g - 1048576;   // < 524288
        const float* p = xs + (size_t)g2 * 8;
        const float4 f0 = *(const float4*)p;
        const float4 f1 = *(const float4*)(p + 4);
        short8 h, l;
        cvt8(f0, f1, h, l);
        *(short8*)(XhiP + (size_t)g2 * 8) = h;
        *(short8*)(XloP + (size_t)g2 * 8) = l;
    }
}

// ---------------------------------------------------------------------------
// R3 GEMM: pure global_load_lds staging from preconverted bf16 hi/lo.
// Zero VALU in the hot loop; 6 DMA issues + 12 ds_read_b128 + 24 MFMA per
// K-step per wave; double-buffered; ONE (vmcnt+lgkm+barrier) per K-step.
// A: per-lane gathered source (exec-masked pad rows over pre-zeroed LDS).
// B: contiguous pre-staged source -> linear LDS (conflict-free).
// ---------------------------------------------------------------------------
__global__ __launch_bounds__(256) void moe_gemm_pc(
    const short* __restrict__ Xhi, const short* __restrict__ Xlo,
    const short* __restrict__ Whi, const short* __restrict__ Wlo,
    const float* __restrict__ bias, const int* __restrict__ ws,
    float* __restrict__ out)
{
    const int tix = blockIdx.y;
    if (tix >= ws[WS_NTILES]) return;
    const int e   = ws[WS_TILE_E + tix];
    const int m0  = ws[WS_TILE_M + tix];
    const int s0  = ws[WS_STARTS + e];
    const int cnt = ws[WS_STARTS + e + 1] - s0;
    const int n0  = blockIdx.x * TN;

    __shared__ short Ahi[2][4 * 512];   // [buf][tile(4)][slot(64)][8]
    __shared__ short Alo[2][4 * 512];
    __shared__ short Bhi[2][8 * 512];   // [buf][tile(8)][slot(64)][8]
    __shared__ short Blo[2][8 * 512];
    __shared__ int   rows_s[TM];

    const int t = threadIdx.x;
    if (t < TM) {
        const int r = m0 + t;
        rows_s[t] = (r < cnt) ? ws[WS_PERM + s0 + r] : -1;
    }
    // zero A bufs so exec-masked pad rows read as 0 in every iteration
    {
        const short8 z = {0, 0, 0, 0, 0, 0, 0, 0};
        ((short8*)&Ahi[0][0])[t] = z;
        ((short8*)&Ahi[1][0])[t] = z;
        ((short8*)&Alo[0][0])[t] = z;
        ((short8*)&Alo[1][0])[t] = z;
    }
    __syncthreads();

    const int lane = t & 63;
    const int wave = t >> 6;
    const int wm = (wave & 1) * 32;   // quadrant m base
    const int wn = (wave >> 1) * 64;  // quadrant n base

    const float zf = 0.f;
    f32x4 acc[2][4];
#pragma unroll
    for (int mi = 0; mi < 2; ++mi)
#pragma unroll
        for (int nj = 0; nj < 4; ++nj)
            acc[mi][nj] = (f32x4){zf, zf, zf, zf};

    // A staging source: wave w stages tile w; lane l -> row w*16+(l&15),
    // k-octet (l>>4). DMA dest = base + l*16B = slot l (fragment layout).
    const int arow = rows_s[wave * 16 + (lane & 15)];
    const bool avalid = arow >= 0;
    const short* aSrcHi = Xhi + (size_t)(avalid ? arow : 0) * D_IN + (lane >> 4) * 8;
    const short* aSrcLo = Xlo + (size_t)(avalid ? arow : 0) * D_IN + (lane >> 4) * 8;

    // B staging source: staged block ((e*32+kt)*8+nt)*4096 shorts; wave w
    // stages tiles w and w+4 (contiguous 1KB per wave-issue).
    const size_t wBase = ((size_t)e * 256 + (size_t)blockIdx.x) * 4096;
    const size_t bo0 = (size_t)wave * 512 + lane * 8;
    const size_t bo1 = (size_t)(wave + 4) * 512 + lane * 8;

#define STAGE(KT, BUF) do {                                                    \
        const int _kt = (KT);                                                  \
        if (avalid) {                                                          \
            __builtin_amdgcn_global_load_lds(                                  \
                (const __attribute__((address_space(1))) void*)(aSrcHi + _kt * 32), \
                (__attribute__((address_space(3))) void*)&Ahi[BUF][wave * 512],\
                16, 0, 0);                                                     \
            __builtin_amdgcn_global_load_lds(                                  \
                (const __attribute__((address_space(1))) void*)(aSrcLo + _kt * 32), \
                (__attribute__((address_space(3))) void*)&Alo[BUF][wave * 512],\
                16, 0, 0);                                                     \
        }                                                                      \
        {                                                                      \
            const size_t _wo = wBase + (size_t)_kt * 32768;                    \
            __builtin_amdgcn_global_load_lds(                                  \
                (const __attribute__((address_space(1))) void*)(Whi + _wo + bo0), \
                (__attribute__((address_space(3))) void*)&Bhi[BUF][wave * 512],\
                16, 0, 0);                                                     \
            __builtin_amdgcn_global_load_lds(                                  \
                (const __attribute__((address_space(1))) void*)(Wlo + _wo + bo0), \
                (__attribute__((address_space(3))) void*)&Blo[BUF][wave * 512],\
                16, 0, 0);                                                     \
            __builtin_amdgcn_global_load_lds(                                  \
                (const __attribute__((address_space(1))) void*)(Whi + _wo + bo1), \
                (__attribute__((address_space(3))) void*)&Bhi[BUF][(wave + 4) * 512], \
                16, 0, 0);                                                     \
            __builtin_amdgcn_global_load_lds(                                  \
                (const __attribute__((address_space(1))) void*)(Wlo + _wo + bo1), \
                (__attribute__((address_space(3))) void*)&Blo[BUF][(wave + 4) * 512], \
                16, 0, 0);                                                     \
        }                                                                      \
    } while (0)

    const int rds = lane * 8;   // linear fragment read, conflict-free

#define FRAG_MFMA(BUF) do {                                                  \
        short8 ah[2], al[2], bh[4], bl[4];                                   \
        _Pragma("unroll")                                                    \
        for (int i2 = 0; i2 < 2; ++i2) {                                     \
            const int aoff = ((wm >> 4) + i2) * 512 + rds;                   \
            ah[i2] = *(const short8*)&Ahi[BUF][aoff];                        \
            al[i2] = *(const short8*)&Alo[BUF][aoff];                        \
        }                                                                    \
        _Pragma("unroll")                                                    \
        for (int i2 = 0; i2 < 4; ++i2) {                                     \
            const int boff = ((wn >> 4) + i2) * 512 + rds;                   \
            bh[i2] = *(const short8*)&Bhi[BUF][boff];                        \
            bl[i2] = *(const short8*)&Blo[BUF][boff];                        \
        }                                                                    \
        _Pragma("unroll")                                                    \
        for (int mi = 0; mi < 2; ++mi)                                       \
            _Pragma("unroll")                                                \
            for (int nj = 0; nj < 4; ++nj) {                                 \
                acc[mi][nj] = __builtin_amdgcn_mfma_f32_16x16x32_bf16(ah[mi], bh[nj], acc[mi][nj], 0, 0, 0); \
                acc[mi][nj] = __builtin_amdgcn_mfma_f32_16x16x32_bf16(ah[mi], bl[nj], acc[mi][nj], 0, 0, 0); \
                acc[mi][nj] = __builtin_amdgcn_mfma_f32_16x16x32_bf16(al[mi], bh[nj], acc[mi][nj], 0, 0, 0); \
            }                                                                \
    } while (0)

    // vmcnt(0): all waves' DMA for the buffer staged this phase completed.
    // lgkmcnt(0): this wave's ds_reads fully drained before barrier (no
    // pending-read vs next-phase-DMA race even if MFMAs sink past the asm).
#define VBAR() asm volatile("s_waitcnt vmcnt(0) lgkmcnt(0)\n\ts_barrier" ::: "memory")

    STAGE(0, 0);
    VBAR();

    int kt = 1;
#pragma unroll 1
    for (int i = 0; i < 15; ++i) {
        STAGE(kt, 1);
        FRAG_MFMA(0);
        VBAR();
        STAGE(kt + 1, 0);
        FRAG_MFMA(1);
        VBAR();
        kt += 2;
    }
    STAGE(31, 1);
    FRAG_MFMA(0);
    VBAR();
    FRAG_MFMA(1);

#undef STAGE
#undef FRAG_MFMA
#undef VBAR

    // Epilogue: C/D layout col=lane&15, row=(lane>>4)*4+reg
    const int cl = lane & 15;
    const int qd = lane >> 4;
    float bv[4];
#pragma unroll
    for (int nj = 0; nj < 4; ++nj)
        bv[nj] = bias[e * D_OUT + n0 + wn + nj * 16 + cl];
#pragma unroll
    for (int mi = 0; mi < 2; ++mi) {
#pragma unroll
        for (int reg = 0; reg < 4; ++reg) {
            const int mloc = wm + mi * 16 + qd * 4 + reg;
            const int r = rows_s[mloc];
            if (r >= 0) {
                float* orow = out + (size_t)r * D_OUT + n0 + wn + cl;
#pragma unroll
                for (int nj = 0; nj < 4; ++nj)
                    orow[nj * 16] = acc[mi][nj][reg] + bv[nj];
            }
        }
    }
}

// ---------------------------------------------------------------------------
// Fallback GEMM (R2, validated 53 us): used only if ws_size < WS_NEEDED.
// ---------------------------------------------------------------------------
__global__ __launch_bounds__(256) void moe_gemm_fb(
    const float* __restrict__ xs, const float* __restrict__ W,
    const float* __restrict__ bias, const int* __restrict__ ws,
    float* __restrict__ out)
{
    const int tix = blockIdx.y;
    if (tix >= ws[WS_NTILES]) return;
    const int e   = ws[WS_TILE_E + tix];
    const int m0  = ws[WS_TILE_M + tix];
    const int s0  = ws[WS_STARTS + e];
    const int cnt = ws[WS_STARTS + e + 1] - s0;
    const int n0  = blockIdx.x * TN;

    __shared__ short Ahi[2][TM * TK];
    __shared__ short Alo[2][TM * TK];
    __shared__ short Bhi[2][TN * TK];
    __shared__ short Blo[2][TN * TK];
    __shared__ int   rows_s[TM];

    const int t = threadIdx.x;
    if (t < TM) {
        const int r = m0 + t;
        rows_s[t] = (r < cnt) ? ws[WS_PERM + s0 + r] : -1;
    }
    __syncthreads();

    const int lane = t & 63;
    const int wave = t >> 6;
    const int wm = (wave & 1) * 32;
    const int wn = (wave >> 1) * 64;

    const float zf = 0.f;
    f32x4 acc[2][4];
#pragma unroll
    for (int mi = 0; mi < 2; ++mi)
#pragma unroll
        for (int nj = 0; nj < 4; ++nj)
            acc[mi][nj] = (f32x4){zf, zf, zf, zf};

    const float* Wb = W + (size_t)e * (D_OUT * (size_t)D_IN) + (size_t)n0 * D_IN;

    const int j  = t & 3;
    const int rr = t >> 2;

    const int arow = rows_s[rr];
    const float* aptr = (arow >= 0) ? (xs + (size_t)arow * D_IN + j * 8) : nullptr;

    const int slotA   = (j * 16 + (rr & 15)) ^ (j << 1);
    const int aoff_st = (rr >> 4) * 512 + slotA * 8;
    const int boff0   = aoff_st;
    const int boff1   = aoff_st + 4 * 512;

    const float* qb0 = Wb + (size_t)rr * D_IN + j * 8;
    const float* qb1 = Wb + (size_t)(64 + rr) * D_IN + j * 8;

    const int rds = (lane ^ ((lane >> 4) << 1)) * 8;

#define LOAD_SET(A0, A1, B0, B1, B2, B3, KOFF) do {                          \
        const int _k = (KOFF);                                               \
        if (aptr) {                                                          \
            A0 = *(const float4*)(aptr + _k);                                \
            A1 = *(const float4*)(aptr + _k + 4);                            \
        }                                                                    \
        B0 = *(const float4*)(qb0 + _k); B1 = *(const float4*)(qb0 + _k + 4);\
        B2 = *(const float4*)(qb1 + _k); B3 = *(const float4*)(qb1 + _k + 4);\
    } while (0)

#define CVT_STORE_SET(A0, A1, B0, B1, B2, B3, BUF) do {                      \
        short8 _h, _l;                                                       \
        cvt8(A0, A1, _h, _l);                                                \
        *(short8*)&Ahi[BUF][aoff_st] = _h; *(short8*)&Alo[BUF][aoff_st] = _l;\
        cvt8(B0, B1, _h, _l);                                                \
        *(short8*)&Bhi[BUF][boff0] = _h;   *(short8*)&Blo[BUF][boff0] = _l;  \
        cvt8(B2, B3, _h, _l);                                                \
        *(short8*)&Bhi[BUF][boff1] = _h;   *(short8*)&Blo[BUF][boff1] = _l;  \
    } while (0)

#define FRAG_MFMA(BUF) do {                                                  \
        short8 ah[2], al[2], bh[4], bl[4];                                   \
        _Pragma("unroll")                                                    \
        for (int i2 = 0; i2 < 2; ++i2) {                                     \
            const int aoff = ((wm >> 4) + i2) * 512 + rds;                   \
            ah[i2] = *(const short8*)&Ahi[BUF][aoff];                        \
            al[i2] = *(const short8*)&Alo[BUF][aoff];                        \
        }                                                                    \
        _Pragma("unroll")                                                    \
        for (int i2 = 0; i2 < 4; ++i2) {                                     \
            const int boff = ((wn >> 4) + i2) * 512 + rds;                   \
            bh[i2] = *(const short8*)&Bhi[BUF][boff];                        \
            bl[i2] = *(const short8*)&Blo[BUF][boff];                        \
        }                                                                    \
        _Pragma("unroll")                                                    \
        for (int mi = 0; mi < 2; ++mi)                                       \
            _Pragma("unroll")                                                \
            for (int nj = 0; nj < 4; ++nj) {                                 \
                acc[mi][nj] = __builtin_amdgcn_mfma_f32_16x16x32_bf16(ah[mi], bh[nj], acc[mi][nj], 0, 0, 0); \
                acc[mi][nj] = __builtin_amdgcn_mfma_f32_16x16x32_bf16(ah[mi], bl[nj], acc[mi][nj], 0, 0, 0); \
                acc[mi][nj] = __builtin_amdgcn_mfma_f32_16x16x32_bf16(al[mi], bh[nj], acc[mi][nj], 0, 0, 0); \
            }                                                                \
    } while (0)

#define PIPE_BARRIER() asm volatile("s_waitcnt lgkmcnt(0)\n\ts_barrier" ::: "memory")

    float4 ax0 = make_float4(0.f, 0.f, 0.f, 0.f), ax1 = ax0;
    float4 bx0, bx1, bx2, bx3;
    float4 ay0 = make_float4(0.f, 0.f, 0.f, 0.f), ay1 = ay0;
    float4 by0, by1, by2, by3;

    LOAD_SET(ax0, ax1, bx0, bx1, bx2, bx3, 0);
    CVT_STORE_SET(ax0, ax1, bx0, bx1, bx2, bx3, 0);
    LOAD_SET(ax0, ax1, bx0, bx1, bx2, bx3, TK);
    PIPE_BARRIER();

    int ke = 2 * TK;
#pragma unroll 1
    for (int i = 0; i < 15; ++i) {
        {
            LOAD_SET(ay0, ay1, by0, by1, by2, by3, ke);
            FRAG_MFMA(0);
            CVT_STORE_SET(ax0, ax1, bx0, bx1, bx2, bx3, 1);
            PIPE_BARRIER();
        }
        {
            LOAD_SET(ax0, ax1, bx0, bx1, bx2, bx3, ke + TK);
            FRAG_MFMA(1);
            CVT_STORE_SET(ay0, ay1, by0, by1, by2, by3, 0);
            PIPE_BARRIER();
        }
        ke += 2 * TK;
    }
    {
        FRAG_MFMA(0);
        CVT_STORE_SET(ax0, ax1, bx0, bx1, bx2, bx3, 1);
        PIPE_BARRIER();
    }
    {
        FRAG_MFMA(1);
    }

#undef LOAD_SET
#undef CVT_STORE_SET
#undef FRAG_MFMA
#undef PIPE_BARRIER

    const int cl = lane & 15;
    const int qd = lane >> 4;
    float bv[4];
#pragma unroll
    for (int nj = 0; nj < 4; ++nj)
        bv[nj] = bias[e * D_OUT + n0 + wn + nj * 16 + cl];
#pragma unroll
    for (int mi = 0; mi < 2; ++mi) {
#pragma unroll
        for (int reg = 0; reg < 4; ++reg) {
            const int mloc = wm + mi * 16 + qd * 4 + reg;
            const int r = rows_s[mloc];
            if (r >= 0) {
                float* orow = out + (size_t)r * D_OUT + n0 + wn + cl;
#pragma unroll
                for (int nj = 0; nj < 4; ++nj)
                    orow[nj * 16] = acc[mi][nj][reg] + bv[nj];
            }
        }
    }
}

extern "C" void kernel_launch(void* const* d_in, const int* in_sizes, int n_in,
                              void* d_out, int out_size, void* d_ws, size_t ws_size,
                              hipStream_t stream) {
    const float* xs      = (const float*)d_in[0];
    const int*   mxs     = (const int*)d_in[1];
    const int*   actions = (const int*)d_in[2];
    const float* W       = (const float*)d_in[3];
    const float* bias    = (const float*)d_in[4];
    float* out = (float*)d_out;
    int*   ws  = (int*)d_ws;
    char*  wsb = (char*)d_ws;

    short* XhiP = (short*)(wsb + WS_XHI_OFF);
    short* XloP = (short*)(wsb + WS_XLO_OFF);
    short* WhiP = (short*)(wsb + WS_WHI_OFF);
    short* WloP = (short*)(wsb + WS_WLO_OFF);

    const int metaOff = BATCH * D_OUT;
    const int meta_mode = (out_size >= metaOff + 3 * BATCH) ? 2
                        : (out_size >= metaOff + 2 * BATCH) ? 1 : 0;

    const bool big = ws_size >= (size_t)WS_NEEDED;
    const int prep_blocks = big ? (17 + 6144) : 17;

    prep_kernel<<<prep_blocks, 256, 0, stream>>>(
        actions, mxs, xs, W, ws, XhiP, XloP, WhiP, WloP, out, meta_mode);

    dim3 grid(D_OUT / TN, MAX_TILES, 1);
    if (big) {
        moe_gemm_pc<<<grid, 256, 0, stream>>>(XhiP, XloP, WhiP, WloP, bias, ws, out);
    } else {
        moe_gemm_fb<<<grid, 256, 0, stream>>>(xs, W, bias, ws, out);
    }
}

// Round 4
// 152.732 us; speedup vs baseline: 1.0060x; 1.0060x over previous
//
#include <hip/hip_runtime.h>

#define BATCH 4096
#define D_IN 1024
#define D_OUT 1024
#define N_EXPERTS 8

#define TM 64
#define TN 128
#define TK 32
#define MAX_TILES 71   // sum ceil(c_e/64) <= 64 + 7

// ws int32 region (slots)
#define WS_PERM    0       // [4096]
#define WS_STARTS  4096    // [9]
#define WS_TILE_E  4112    // [71]
#define WS_TILE_M  4200    // [71]
#define WS_NTILES  4288    // [1]

// staged bf16 regions (byte offsets into ws)
#define WS_XHI_OFF   32768
#define WS_XLO_OFF   (32768 + 8388608)
#define WS_WHI_OFF   (32768 + 2*8388608)
#define WS_WLO_OFF   (32768 + 2*8388608 + 16777216)
#define WS_NEEDED    (32768 + 2*8388608 + 2*16777216)   // 50,364,416 B

typedef __attribute__((ext_vector_type(8))) short short8;   // 8 x bf16
typedef __attribute__((ext_vector_type(4))) float f32x4;

// fp32 -> bf16 hi/lo split (truncation; lo = next 8 mantissa bits). Unchanged.
__device__ __forceinline__ void cvt8(const float4 a, const float4 b,
                                     short8& h, short8& l) {
    float f[8] = {a.x, a.y, a.z, a.w, b.x, b.y, b.z, b.w};
#pragma unroll
    for (int i = 0; i < 8; ++i) {
        const unsigned u = __float_as_uint(f[i]);
        h[i] = (short)(u >> 16);
        const float r = f[i] - __uint_as_float(u & 0xffff0000u);
        l[i] = (short)(__float_as_uint(r) >> 16);
    }
}

// ---------------------------------------------------------------------------
// Fused prep kernel (validated R3):
//   block 0      : ballot-based grouping
//   blocks 1..16 : meta tail writes
//   blocks 17+   : stream-convert W -> Whi/Wlo (fragment-staged order) and
//                  xs -> Xhi/Xlo (row-major).
// ---------------------------------------------------------------------------
__global__ __launch_bounds__(256) void prep_kernel(
    const int* __restrict__ actions, const int* __restrict__ mxs,
    const float* __restrict__ xs, const float* __restrict__ W,
    int* __restrict__ ws,
    short* __restrict__ XhiP, short* __restrict__ XloP,
    short* __restrict__ WhiP, short* __restrict__ WloP,
    float* __restrict__ out, int meta_mode)
{
    const int bid = blockIdx.x;
    const int t = threadIdx.x;

    if (bid == 0) {
        __shared__ int chunkoff[64][N_EXPERTS];
        const int lane = t & 63;
        const int wave = t >> 6;

        for (int it = 0; it < 16; ++it) {
            const int c = wave * 16 + it;
            const int a = actions[c * 64 + lane];
            int myc = 0;
#pragma unroll
            for (int e = 0; e < N_EXPERTS; ++e) {
                const unsigned long long me = __ballot(a == e);
                if (lane == e) myc = (int)__popcll(me);
            }
            if (lane < N_EXPERTS) chunkoff[c][lane] = myc;
        }
        __syncthreads();

        if (wave == 0) {
            int cc0 = chunkoff[lane][0], cc1 = chunkoff[lane][1];
            int cc2 = chunkoff[lane][2], cc3 = chunkoff[lane][3];
            int cc4 = chunkoff[lane][4], cc5 = chunkoff[lane][5];
            int cc6 = chunkoff[lane][6], cc7 = chunkoff[lane][7];
            int tot0, tot1, tot2, tot3, tot4, tot5, tot6, tot7;
            int ex0, ex1, ex2, ex3, ex4, ex5, ex6, ex7;
#define SCAN1(CC, TOT, EX) do {                                   \
            int v = CC;                                           \
            _Pragma("unroll")                                     \
            for (int d = 1; d < 64; d <<= 1) {                    \
                const int u = __shfl_up(v, d, 64);                \
                if (lane >= d) v += u;                            \
            }                                                     \
            TOT = __shfl(v, 63, 64);                              \
            EX = v - CC;                                          \
        } while (0)
            SCAN1(cc0, tot0, ex0); SCAN1(cc1, tot1, ex1);
            SCAN1(cc2, tot2, ex2); SCAN1(cc3, tot3, ex3);
            SCAN1(cc4, tot4, ex4); SCAN1(cc5, tot5, ex5);
            SCAN1(cc6, tot6, ex6); SCAN1(cc7, tot7, ex7);
#undef SCAN1
            const int b0 = 0;
            const int b1 = b0 + tot0, b2 = b1 + tot1, b3 = b2 + tot2;
            const int b4 = b3 + tot3, b5 = b4 + tot4, b6 = b5 + tot5;
            const int b7 = b6 + tot6;
            chunkoff[lane][0] = b0 + ex0; chunkoff[lane][1] = b1 + ex1;
            chunkoff[lane][2] = b2 + ex2; chunkoff[lane][3] = b3 + ex3;
            chunkoff[lane][4] = b4 + ex4; chunkoff[lane][5] = b5 + ex5;
            chunkoff[lane][6] = b6 + ex6; chunkoff[lane][7] = b7 + ex7;
            if (lane == 0) {
                ws[WS_STARTS + 0] = b0; ws[WS_STARTS + 1] = b1;
                ws[WS_STARTS + 2] = b2; ws[WS_STARTS + 3] = b3;
                ws[WS_STARTS + 4] = b4; ws[WS_STARTS + 5] = b5;
                ws[WS_STARTS + 6] = b6; ws[WS_STARTS + 7] = b7;
                ws[WS_STARTS + 8] = BATCH;
                int nt = 0;
                int tots[8] = {tot0, tot1, tot2, tot3, tot4, tot5, tot6, tot7};
#pragma unroll
                for (int e = 0; e < N_EXPERTS; ++e)
                    for (int m0 = 0; m0 < tots[e]; m0 += TM) {
                        ws[WS_TILE_E + nt] = e;
                        ws[WS_TILE_M + nt] = m0;
                        ++nt;
                    }
                ws[WS_NTILES] = nt;
            }
        }
        __syncthreads();

        for (int it = 0; it < 16; ++it) {
            const int c = wave * 16 + it;
            const int i = c * 64 + lane;
            const int a = actions[i];
            unsigned long long msel = 0;
#pragma unroll
            for (int e = 0; e < N_EXPERTS; ++e) {
                const unsigned long long me = __ballot(a == e);
                if (a == e) msel = me;
            }
            const int rank = (int)__popcll(msel & ((1ull << lane) - 1ull));
            const int pos = chunkoff[c][a] + rank;
            ws[WS_PERM + pos] = i;
        }
        return;
    }

    if (bid <= 16) {
        const int i = (bid - 1) * 256 + t;
        if (meta_mode == 2) {
            out[BATCH * D_OUT + i] = (float)mxs[i];
            long long* a64 = (long long*)(out + BATCH * D_OUT + BATCH);
            a64[i] = (long long)actions[i];
        } else if (meta_mode == 1) {
            out[BATCH * D_OUT + i] = (float)mxs[i];
            out[BATCH * D_OUT + BATCH + i] = (float)actions[i];
        }
        return;
    }

    const int g = (bid - 17) * 256 + t;
    if (g < 1048576) {
        // g = (((e*32+kt)*8+nt)*8 + i2)*64 + slot ; slot = j*16 + c
        const int slot = g & 63;
        const int i2   = (g >> 6) & 7;
        const int blk  = g >> 9;
        const int nt   = blk & 7;
        const int kt   = (blk >> 3) & 31;
        const int e    = blk >> 8;
        const int c    = slot & 15;
        const int j    = slot >> 4;
        const int n    = nt * 128 + i2 * 16 + c;
        const float* p = W + ((size_t)(e << 10) + n) * D_IN + kt * 32 + j * 8;
        const float4 f0 = *(const float4*)p;
        const float4 f1 = *(const float4*)(p + 4);
        short8 h, l;
        cvt8(f0, f1, h, l);
        *(short8*)(WhiP + (size_t)g * 8) = h;
        *(short8*)(WloP + (size_t)g * 8) = l;
    } else {
        const int g2 = g - 1048576;   // < 524288
        const float* p = xs + (size_t)g2 * 8;
        const float4 f0 = *(const float4*)p;
        const float4 f1 = *(const float4*)(p + 4);
        short8 h, l;
        cvt8(f0, f1, h, l);
        *(short8*)(XhiP + (size_t)g2 * 8) = h;
        *(short8*)(XloP + (size_t)g2 * 8) = l;
    }
}

// ---------------------------------------------------------------------------
// R4 GEMM: counted-vmcnt double-buffer (T4) + XCD-chunked swizzle (T1).
// Per K-step: wait vmcnt(6) [current buf done, next tile's 6 in flight] ->
// barrier -> 12 ds_read + 24 MFMA -> lgkmcnt(0)+barrier [buf free] ->
// stage tile t+2 into freed buf. vmcnt NEVER drains to 0 in the loop.
// A-DMA always issued (clamped row): uniform 6 loads/STAGE/wave so the
// vmcnt arithmetic holds; pad-row acc is garbage but never stored.
// Grid: 568 1-D blocks; nsl = wid&7 (one n-slice per XCD -> its 512KB
// W-slice per expert stays L2-resident across the 32 K-step re-reads),
// tix = wid>>3.
// ---------------------------------------------------------------------------
__global__ __launch_bounds__(256) void moe_gemm_pc(
    const short* __restrict__ Xhi, const short* __restrict__ Xlo,
    const short* __restrict__ Whi, const short* __restrict__ Wlo,
    const float* __restrict__ bias, const int* __restrict__ ws,
    float* __restrict__ out)
{
    const int wid = blockIdx.x;
    const int nsl = wid & 7;         // n-slice 0..7 == XCD id under round-robin
    const int tix = wid >> 3;        // tile 0..70
    if (tix >= ws[WS_NTILES]) return;
    const int e   = ws[WS_TILE_E + tix];
    const int m0  = ws[WS_TILE_M + tix];
    const int s0  = ws[WS_STARTS + e];
    const int cnt = ws[WS_STARTS + e + 1] - s0;
    const int n0  = nsl * TN;

    __shared__ short Ahi[2][4 * 512];   // [buf][tile(4)][slot(64)][8]
    __shared__ short Alo[2][4 * 512];
    __shared__ short Bhi[2][8 * 512];   // [buf][tile(8)][slot(64)][8]
    __shared__ short Blo[2][8 * 512];
    __shared__ int   rows_s[TM];

    const int t = threadIdx.x;
    if (t < TM) {
        const int r = m0 + t;
        rows_s[t] = (r < cnt) ? ws[WS_PERM + s0 + r] : -1;
    }
    __syncthreads();

    const int lane = t & 63;
    const int wave = t >> 6;
    const int wm = (wave & 1) * 32;   // quadrant m base
    const int wn = (wave >> 1) * 64;  // quadrant n base

    const float zf = 0.f;
    f32x4 acc[2][4];
#pragma unroll
    for (int mi = 0; mi < 2; ++mi)
#pragma unroll
        for (int nj = 0; nj < 4; ++nj)
            acc[mi][nj] = (f32x4){zf, zf, zf, zf};

    // A staging source: wave w stages tile w; lane l -> row w*16+(l&15),
    // k-octet (l>>4). Clamped row for pads (always-issue -> uniform vmcnt).
    const int arow0 = rows_s[wave * 16 + (lane & 15)];
    const int arow  = arow0 < 0 ? 0 : arow0;
    const short* aSrcHi = Xhi + (size_t)arow * D_IN + (lane >> 4) * 8;
    const short* aSrcLo = Xlo + (size_t)arow * D_IN + (lane >> 4) * 8;

    // B staging source: staged block ((e*32+kt)*8+nsl)*4096 shorts.
    const size_t wBase = ((size_t)e * 256 + (size_t)nsl) * 4096;
    const size_t bo0 = (size_t)wave * 512 + lane * 8;
    const size_t bo1 = (size_t)(wave + 4) * 512 + lane * 8;

#define STAGE(KT, BUF) do {                                                    \
        const int _kt = (KT);                                                  \
        __builtin_amdgcn_global_load_lds(                                      \
            (const __attribute__((address_space(1))) void*)(aSrcHi + _kt * 32),\
            (__attribute__((address_space(3))) void*)&Ahi[BUF][wave * 512],    \
            16, 0, 0);                                                         \
        __builtin_amdgcn_global_load_lds(                                      \
            (const __attribute__((address_space(1))) void*)(aSrcLo + _kt * 32),\
            (__attribute__((address_space(3))) void*)&Alo[BUF][wave * 512],    \
            16, 0, 0);                                                         \
        {                                                                      \
            const size_t _wo = wBase + (size_t)_kt * 32768;                    \
            __builtin_amdgcn_global_load_lds(                                  \
                (const __attribute__((address_space(1))) void*)(Whi + _wo + bo0), \
                (__attribute__((address_space(3))) void*)&Bhi[BUF][wave * 512],\
                16, 0, 0);                                                     \
            __builtin_amdgcn_global_load_lds(                                  \
                (const __attribute__((address_space(1))) void*)(Wlo + _wo + bo0), \
                (__attribute__((address_space(3))) void*)&Blo[BUF][wave * 512],\
                16, 0, 0);                                                     \
            __builtin_amdgcn_global_load_lds(                                  \
                (const __attribute__((address_space(1))) void*)(Whi + _wo + bo1), \
                (__attribute__((address_space(3))) void*)&Bhi[BUF][(wave + 4) * 512], \
                16, 0, 0);                                                     \
            __builtin_amdgcn_global_load_lds(                                  \
                (const __attribute__((address_space(1))) void*)(Wlo + _wo + bo1), \
                (__attribute__((address_space(3))) void*)&Blo[BUF][(wave + 4) * 512], \
                16, 0, 0);                                                     \
        }                                                                      \
    } while (0)

    const int rds = lane * 8;   // linear fragment read, conflict-free

#define FRAG_MFMA(BUF) do {                                                  \
        short8 ah[2], al[2], bh[4], bl[4];                                   \
        _Pragma("unroll")                                                    \
        for (int i2 = 0; i2 < 2; ++i2) {                                     \
            const int aoff = ((wm >> 4) + i2) * 512 + rds;                   \
            ah[i2] = *(const short8*)&Ahi[BUF][aoff];                        \
            al[i2] = *(const short8*)&Alo[BUF][aoff];                        \
        }                                                                    \
        _Pragma("unroll")                                                    \
        for (int i2 = 0; i2 < 4; ++i2) {                                     \
            const int boff = ((wn >> 4) + i2) * 512 + rds;                   \
            bh[i2] = *(const short8*)&Bhi[BUF][boff];                        \
            bl[i2] = *(const short8*)&Blo[BUF][boff];                        \
        }                                                                    \
        _Pragma("unroll")                                                    \
        for (int mi = 0; mi < 2; ++mi)                                       \
            _Pragma("unroll")                                                \
            for (int nj = 0; nj < 4; ++nj) {                                 \
                acc[mi][nj] = __builtin_amdgcn_mfma_f32_16x16x32_bf16(ah[mi], bh[nj], acc[mi][nj], 0, 0, 0); \
                acc[mi][nj] = __builtin_amdgcn_mfma_f32_16x16x32_bf16(ah[mi], bl[nj], acc[mi][nj], 0, 0, 0); \
                acc[mi][nj] = __builtin_amdgcn_mfma_f32_16x16x32_bf16(al[mi], bh[nj], acc[mi][nj], 0, 0, 0); \
            }                                                                \
    } while (0)

    // wait for current buf's DMA (oldest 6 of 12) -> all waves agree
#define WAIT6_BAR() asm volatile("s_waitcnt vmcnt(6)\n\ts_barrier" ::: "memory")
#define WAIT0_BAR() asm volatile("s_waitcnt vmcnt(0)\n\ts_barrier" ::: "memory")
    // my ds_reads landed in regs -> all waves' reads done -> buf free
#define READ_FENCE() asm volatile("s_waitcnt lgkmcnt(0)\n\ts_barrier" ::: "memory")

    // prologue: stage tiles 0,1 -> 12 outstanding
    STAGE(0, 0);
    STAGE(1, 1);

    int kt = 2;
#pragma unroll 1
    for (int i = 0; i < 15; ++i) {
        WAIT6_BAR();          // S(2i) done; S(2i+1) in flight
        FRAG_MFMA(0);
        READ_FENCE();
        STAGE(kt, 0);         // tile 2i+2
        WAIT6_BAR();          // S(2i+1) done; S(2i+2) in flight
        FRAG_MFMA(1);
        READ_FENCE();
        STAGE(kt + 1, 1);     // tile 2i+3
        kt += 2;
    }
    WAIT6_BAR();              // S(30) done; S(31) in flight
    FRAG_MFMA(0);
    WAIT0_BAR();              // S(31) done
    FRAG_MFMA(1);

#undef STAGE
#undef FRAG_MFMA
#undef WAIT6_BAR
#undef WAIT0_BAR
#undef READ_FENCE

    // Epilogue: C/D layout col=lane&15, row=(lane>>4)*4+reg
    const int cl = lane & 15;
    const int qd = lane >> 4;
    float bv[4];
#pragma unroll
    for (int nj = 0; nj < 4; ++nj)
        bv[nj] = bias[e * D_OUT + n0 + wn + nj * 16 + cl];
#pragma unroll
    for (int mi = 0; mi < 2; ++mi) {
#pragma unroll
        for (int reg = 0; reg < 4; ++reg) {
            const int mloc = wm + mi * 16 + qd * 4 + reg;
            const int r = rows_s[mloc];
            if (r >= 0) {
                float* orow = out + (size_t)r * D_OUT + n0 + wn + cl;
#pragma unroll
                for (int nj = 0; nj < 4; ++nj)
                    orow[nj * 16] = acc[mi][nj][reg] + bv[nj];
            }
        }
    }
}

// ---------------------------------------------------------------------------
// Fallback GEMM (R2, validated): used only if ws_size < WS_NEEDED.
// ---------------------------------------------------------------------------
__global__ __launch_bounds__(256) void moe_gemm_fb(
    const float* __restrict__ xs, const float* __restrict__ W,
    const float* __restrict__ bias, const int* __restrict__ ws,
    float* __restrict__ out)
{
    const int tix = blockIdx.y;
    if (tix >= ws[WS_NTILES]) return;
    const int e   = ws[WS_TILE_E + tix];
    const int m0  = ws[WS_TILE_M + tix];
    const int s0  = ws[WS_STARTS + e];
    const int cnt = ws[WS_STARTS + e + 1] - s0;
    const int n0  = blockIdx.x * TN;

    __shared__ short Ahi[2][TM * TK];
    __shared__ short Alo[2][TM * TK];
    __shared__ short Bhi[2][TN * TK];
    __shared__ short Blo[2][TN * TK];
    __shared__ int   rows_s[TM];

    const int t = threadIdx.x;
    if (t < TM) {
        const int r = m0 + t;
        rows_s[t] = (r < cnt) ? ws[WS_PERM + s0 + r] : -1;
    }
    __syncthreads();

    const int lane = t & 63;
    const int wave = t >> 6;
    const int wm = (wave & 1) * 32;
    const int wn = (wave >> 1) * 64;

    const float zf = 0.f;
    f32x4 acc[2][4];
#pragma unroll
    for (int mi = 0; mi < 2; ++mi)
#pragma unroll
        for (int nj = 0; nj < 4; ++nj)
            acc[mi][nj] = (f32x4){zf, zf, zf, zf};

    const float* Wb = W + (size_t)e * (D_OUT * (size_t)D_IN) + (size_t)n0 * D_IN;

    const int j  = t & 3;
    const int rr = t >> 2;

    const int arow = rows_s[rr];
    const float* aptr = (arow >= 0) ? (xs + (size_t)arow * D_IN + j * 8) : nullptr;

    const int slotA   = (j * 16 + (rr & 15)) ^ (j << 1);
    const int aoff_st = (rr >> 4) * 512 + slotA * 8;
    const int boff0   = aoff_st;
    const int boff1   = aoff_st + 4 * 512;

    const float* qb0 = Wb + (size_t)rr * D_IN + j * 8;
    const float* qb1 = Wb + (size_t)(64 + rr) * D_IN + j * 8;

    const int rds = (lane ^ ((lane >> 4) << 1)) * 8;

#define LOAD_SET(A0, A1, B0, B1, B2, B3, KOFF) do {                          \
        const int _k = (KOFF);                                               \
        if (aptr) {                                                          \
            A0 = *(const float4*)(aptr + _k);                                \
            A1 = *(const float4*)(aptr + _k + 4);                            \
        }                                                                    \
        B0 = *(const float4*)(qb0 + _k); B1 = *(const float4*)(qb0 + _k + 4);\
        B2 = *(const float4*)(qb1 + _k); B3 = *(const float4*)(qb1 + _k + 4);\
    } while (0)

#define CVT_STORE_SET(A0, A1, B0, B1, B2, B3, BUF) do {                      \
        short8 _h, _l;                                                       \
        cvt8(A0, A1, _h, _l);                                                \
        *(short8*)&Ahi[BUF][aoff_st] = _h; *(short8*)&Alo[BUF][aoff_st] = _l;\
        cvt8(B0, B1, _h, _l);                                                \
        *(short8*)&Bhi[BUF][boff0] = _h;   *(short8*)&Blo[BUF][boff0] = _l;  \
        cvt8(B2, B3, _h, _l);                                                \
        *(short8*)&Bhi[BUF][boff1] = _h;   *(short8*)&Blo[BUF][boff1] = _l;  \
    } while (0)

#define FRAG_MFMA(BUF) do {                                                  \
        short8 ah[2], al[2], bh[4], bl[4];                                   \
        _Pragma("unroll")                                                    \
        for (int i2 = 0; i2 < 2; ++i2) {                                     \
            const int aoff = ((wm >> 4) + i2) * 512 + rds;                   \
            ah[i2] = *(const short8*)&Ahi[BUF][aoff];                        \
            al[i2] = *(const short8*)&Alo[BUF][aoff];                        \
        }                                                                    \
        _Pragma("unroll")                                                    \
        for (int i2 = 0; i2 < 4; ++i2) {                                     \
            const int boff = ((wn >> 4) + i2) * 512 + rds;                   \
            bh[i2] = *(const short8*)&Bhi[BUF][boff];                        \
            bl[i2] = *(const short8*)&Blo[BUF][boff];                        \
        }                                                                    \
        _Pragma("unroll")                                                    \
        for (int mi = 0; mi < 2; ++mi)                                       \
            _Pragma("unroll")                                                \
            for (int nj = 0; nj < 4; ++nj) {                                 \
                acc[mi][nj] = __builtin_amdgcn_mfma_f32_16x16x32_bf16(ah[mi], bh[nj], acc[mi][nj], 0, 0, 0); \
                acc[mi][nj] = __builtin_amdgcn_mfma_f32_16x16x32_bf16(ah[mi], bl[nj], acc[mi][nj], 0, 0, 0); \
                acc[mi][nj] = __builtin_amdgcn_mfma_f32_16x16x32_bf16(al[mi], bh[nj], acc[mi][nj], 0, 0, 0); \
            }                                                                \
    } while (0)

#define PIPE_BARRIER() asm volatile("s_waitcnt lgkmcnt(0)\n\ts_barrier" ::: "memory")

    float4 ax0 = make_float4(0.f, 0.f, 0.f, 0.f), ax1 = ax0;
    float4 bx0, bx1, bx2, bx3;
    float4 ay0 = make_float4(0.f, 0.f, 0.f, 0.f), ay1 = ay0;
    float4 by0, by1, by2, by3;

    LOAD_SET(ax0, ax1, bx0, bx1, bx2, bx3, 0);
    CVT_STORE_SET(ax0, ax1, bx0, bx1, bx2, bx3, 0);
    LOAD_SET(ax0, ax1, bx0, bx1, bx2, bx3, TK);
    PIPE_BARRIER();

    int ke = 2 * TK;
#pragma unroll 1
    for (int i = 0; i < 15; ++i) {
        {
            LOAD_SET(ay0, ay1, by0, by1, by2, by3, ke);
            FRAG_MFMA(0);
            CVT_STORE_SET(ax0, ax1, bx0, bx1, bx2, bx3, 1);
            PIPE_BARRIER();
        }
        {
            LOAD_SET(ax0, ax1, bx0, bx1, bx2, bx3, ke + TK);
            FRAG_MFMA(1);
            CVT_STORE_SET(ay0, ay1, by0, by1, by2, by3, 0);
            PIPE_BARRIER();
        }
        ke += 2 * TK;
    }
    {
        FRAG_MFMA(0);
        CVT_STORE_SET(ax0, ax1, bx0, bx1, bx2, bx3, 1);
        PIPE_BARRIER();
    }
    {
        FRAG_MFMA(1);
    }

#undef LOAD_SET
#undef CVT_STORE_SET
#undef FRAG_MFMA
#undef PIPE_BARRIER

    const int cl = lane & 15;
    const int qd = lane >> 4;
    float bv[4];
#pragma unroll
    for (int nj = 0; nj < 4; ++nj)
        bv[nj] = bias[e * D_OUT + n0 + wn + nj * 16 + cl];
#pragma unroll
    for (int mi = 0; mi < 2; ++mi) {
#pragma unroll
        for (int reg = 0; reg < 4; ++reg) {
            const int mloc = wm + mi * 16 + qd * 4 + reg;
            const int r = rows_s[mloc];
            if (r >= 0) {
                float* orow = out + (size_t)r * D_OUT + n0 + wn + cl;
#pragma unroll
                for (int nj = 0; nj < 4; ++nj)
                    orow[nj * 16] = acc[mi][nj][reg] + bv[nj];
            }
        }
    }
}

extern "C" void kernel_launch(void* const* d_in, const int* in_sizes, int n_in,
                              void* d_out, int out_size, void* d_ws, size_t ws_size,
                              hipStream_t stream) {
    const float* xs      = (const float*)d_in[0];
    const int*   mxs     = (const int*)d_in[1];
    const int*   actions = (const int*)d_in[2];
    const float* W       = (const float*)d_in[3];
    const float* bias    = (const float*)d_in[4];
    float* out = (float*)d_out;
    int*   ws  = (int*)d_ws;
    char*  wsb = (char*)d_ws;

    short* XhiP = (short*)(wsb + WS_XHI_OFF);
    short* XloP = (short*)(wsb + WS_XLO_OFF);
    short* WhiP = (short*)(wsb + WS_WHI_OFF);
    short* WloP = (short*)(wsb + WS_WLO_OFF);

    const int metaOff = BATCH * D_OUT;
    const int meta_mode = (out_size >= metaOff + 3 * BATCH) ? 2
                        : (out_size >= metaOff + 2 * BATCH) ? 1 : 0;

    const bool big = ws_size >= (size_t)WS_NEEDED;
    const int prep_blocks = big ? (17 + 6144) : 17;

    prep_kernel<<<prep_blocks, 256, 0, stream>>>(
        actions, mxs, xs, W, ws, XhiP, XloP, WhiP, WloP, out, meta_mode);

    if (big) {
        moe_gemm_pc<<<8 * MAX_TILES, 256, 0, stream>>>(XhiP, XloP, WhiP, WloP, bias, ws, out);
    } else {
        dim3 grid(D_OUT / TN, MAX_TILES, 1);
        moe_gemm_fb<<<grid, 256, 0, stream>>>(xs, W, bias, ws, out);
    }
}

// Round 5
// 147.768 us; speedup vs baseline: 1.0398x; 1.0336x over previous
//
#include <hip/hip_runtime.h>

#define BATCH 4096
#define D_IN 1024
#define D_OUT 1024
#define N_EXPERTS 8

#define TK 32
#define MAX_TILES 71        // TM=64 list bound (fallback)
#define MAX_TILES_128 39    // TM=128: 32 + 7

// ws int32 region (slots)
#define WS_PERM    0       // [4096]
#define WS_STARTS  4096    // [9]
#define WS_TILE_E  4112    // [71]
#define WS_TILE_M  4200    // [71]
#define WS_NTILES  4288    // [1]

// staged bf16 regions (byte offsets into ws)
#define WS_XHI_OFF   32768
#define WS_XLO_OFF   (32768 + 8388608)
#define WS_WHI_OFF   (32768 + 2*8388608)
#define WS_WLO_OFF   (32768 + 2*8388608 + 16777216)
#define WS_NEEDED    (32768 + 2*8388608 + 2*16777216)   // 50,364,416 B

typedef __attribute__((ext_vector_type(8))) short short8;   // 8 x bf16
typedef __attribute__((ext_vector_type(4))) float f32x4;

// fp32 -> bf16 hi/lo split (truncation; lo = next 8 mantissa bits). Unchanged.
__device__ __forceinline__ void cvt8(const float4 a, const float4 b,
                                     short8& h, short8& l) {
    float f[8] = {a.x, a.y, a.z, a.w, b.x, b.y, b.z, b.w};
#pragma unroll
    for (int i = 0; i < 8; ++i) {
        const unsigned u = __float_as_uint(f[i]);
        h[i] = (short)(u >> 16);
        const float r = f[i] - __uint_as_float(u & 0xffff0000u);
        l[i] = (short)(__float_as_uint(r) >> 16);
    }
}

// ---------------------------------------------------------------------------
// Fused prep kernel (validated R3/R4). tm_tile parameterizes the tile list
// (128 for the pc path, 64 for the fallback).
// ---------------------------------------------------------------------------
__global__ __launch_bounds__(256) void prep_kernel(
    const int* __restrict__ actions, const int* __restrict__ mxs,
    const float* __restrict__ xs, const float* __restrict__ W,
    int* __restrict__ ws,
    short* __restrict__ XhiP, short* __restrict__ XloP,
    short* __restrict__ WhiP, short* __restrict__ WloP,
    float* __restrict__ out, int meta_mode, int tm_tile)
{
    const int bid = blockIdx.x;
    const int t = threadIdx.x;

    if (bid == 0) {
        __shared__ int chunkoff[64][N_EXPERTS];
        const int lane = t & 63;
        const int wave = t >> 6;

        for (int it = 0; it < 16; ++it) {
            const int c = wave * 16 + it;
            const int a = actions[c * 64 + lane];
            int myc = 0;
#pragma unroll
            for (int e = 0; e < N_EXPERTS; ++e) {
                const unsigned long long me = __ballot(a == e);
                if (lane == e) myc = (int)__popcll(me);
            }
            if (lane < N_EXPERTS) chunkoff[c][lane] = myc;
        }
        __syncthreads();

        if (wave == 0) {
            int cc0 = chunkoff[lane][0], cc1 = chunkoff[lane][1];
            int cc2 = chunkoff[lane][2], cc3 = chunkoff[lane][3];
            int cc4 = chunkoff[lane][4], cc5 = chunkoff[lane][5];
            int cc6 = chunkoff[lane][6], cc7 = chunkoff[lane][7];
            int tot0, tot1, tot2, tot3, tot4, tot5, tot6, tot7;
            int ex0, ex1, ex2, ex3, ex4, ex5, ex6, ex7;
#define SCAN1(CC, TOT, EX) do {                                   \
            int v = CC;                                           \
            _Pragma("unroll")                                     \
            for (int d = 1; d < 64; d <<= 1) {                    \
                const int u = __shfl_up(v, d, 64);                \
                if (lane >= d) v += u;                            \
            }                                                     \
            TOT = __shfl(v, 63, 64);                              \
            EX = v - CC;                                          \
        } while (0)
            SCAN1(cc0, tot0, ex0); SCAN1(cc1, tot1, ex1);
            SCAN1(cc2, tot2, ex2); SCAN1(cc3, tot3, ex3);
            SCAN1(cc4, tot4, ex4); SCAN1(cc5, tot5, ex5);
            SCAN1(cc6, tot6, ex6); SCAN1(cc7, tot7, ex7);
#undef SCAN1
            const int b0 = 0;
            const int b1 = b0 + tot0, b2 = b1 + tot1, b3 = b2 + tot2;
            const int b4 = b3 + tot3, b5 = b4 + tot4, b6 = b5 + tot5;
            const int b7 = b6 + tot6;
            chunkoff[lane][0] = b0 + ex0; chunkoff[lane][1] = b1 + ex1;
            chunkoff[lane][2] = b2 + ex2; chunkoff[lane][3] = b3 + ex3;
            chunkoff[lane][4] = b4 + ex4; chunkoff[lane][5] = b5 + ex5;
            chunkoff[lane][6] = b6 + ex6; chunkoff[lane][7] = b7 + ex7;
            if (lane == 0) {
                ws[WS_STARTS + 0] = b0; ws[WS_STARTS + 1] = b1;
                ws[WS_STARTS + 2] = b2; ws[WS_STARTS + 3] = b3;
                ws[WS_STARTS + 4] = b4; ws[WS_STARTS + 5] = b5;
                ws[WS_STARTS + 6] = b6; ws[WS_STARTS + 7] = b7;
                ws[WS_STARTS + 8] = BATCH;
                int nt = 0;
                int tots[8] = {tot0, tot1, tot2, tot3, tot4, tot5, tot6, tot7};
#pragma unroll
                for (int e = 0; e < N_EXPERTS; ++e)
                    for (int m0 = 0; m0 < tots[e]; m0 += tm_tile) {
                        ws[WS_TILE_E + nt] = e;
                        ws[WS_TILE_M + nt] = m0;
                        ++nt;
                    }
                ws[WS_NTILES] = nt;
            }
        }
        __syncthreads();

        for (int it = 0; it < 16; ++it) {
            const int c = wave * 16 + it;
            const int i = c * 64 + lane;
            const int a = actions[i];
            unsigned long long msel = 0;
#pragma unroll
            for (int e = 0; e < N_EXPERTS; ++e) {
                const unsigned long long me = __ballot(a == e);
                if (a == e) msel = me;
            }
            const int rank = (int)__popcll(msel & ((1ull << lane) - 1ull));
            const int pos = chunkoff[c][a] + rank;
            ws[WS_PERM + pos] = i;
        }
        return;
    }

    if (bid <= 16) {
        const int i = (bid - 1) * 256 + t;
        if (meta_mode == 2) {
            out[BATCH * D_OUT + i] = (float)mxs[i];
            long long* a64 = (long long*)(out + BATCH * D_OUT + BATCH);
            a64[i] = (long long)actions[i];
        } else if (meta_mode == 1) {
            out[BATCH * D_OUT + i] = (float)mxs[i];
            out[BATCH * D_OUT + BATCH + i] = (float)actions[i];
        }
        return;
    }

    const int g = (bid - 17) * 256 + t;
    if (g < 1048576) {
        // g = (((e*32+kt)*8+nt)*8 + i2)*64 + slot ; slot = j*16 + c
        const int slot = g & 63;
        const int i2   = (g >> 6) & 7;
        const int blk  = g >> 9;
        const int nt   = blk & 7;
        const int kt   = (blk >> 3) & 31;
        const int e    = blk >> 8;
        const int c    = slot & 15;
        const int j    = slot >> 4;
        const int n    = nt * 128 + i2 * 16 + c;
        const float* p = W + ((size_t)(e << 10) + n) * D_IN + kt * 32 + j * 8;
        const float4 f0 = *(const float4*)p;
        const float4 f1 = *(const float4*)(p + 4);
        short8 h, l;
        cvt8(f0, f1, h, l);
        *(short8*)(WhiP + (size_t)g * 8) = h;
        *(short8*)(WloP + (size_t)g * 8) = l;
    } else {
        const int g2 = g - 1048576;   // < 524288
        const float* p = xs + (size_t)g2 * 8;
        const float4 f0 = *(const float4*)p;
        const float4 f1 = *(const float4*)(p + 4);
        short8 h, l;
        cvt8(f0, f1, h, l);
        *(short8*)(XhiP + (size_t)g2 * 8) = h;
        *(short8*)(XloP + (size_t)g2 * 8) = l;
    }
}

// ---------------------------------------------------------------------------
// R5 GEMM: 128x128 tile, 8 waves. Request-BW model: bytes requested per
// output tile ~ (1/TM+1/TN); 64x128 -> 405 MB aggregate, 128x128 -> 270 MB.
// Per-wave inner loop identical to R4 (32x64 quadrant, 24 MFMA, 12 ds_read,
// 4 uniform DMA/stage, counted vmcnt(4), never drained in-loop).
// Index remap: the 8 n-slice blocks sharing one A m-tile sit on ONE XCD
// (wid%8 == tix%8) so A's 8x reuse is L2-served instead of L3.
//   xcd = wid&7 ; j = wid>>3 ; nsl = j&7 ; tix = (j>>3)*8 + xcd
// ---------------------------------------------------------------------------
#define TM5 128
#define TN5 128

__global__ __launch_bounds__(512) void moe_gemm_pc(
    const short* __restrict__ Xhi, const short* __restrict__ Xlo,
    const short* __restrict__ Whi, const short* __restrict__ Wlo,
    const float* __restrict__ bias, const int* __restrict__ ws,
    float* __restrict__ out)
{
    const int wid = blockIdx.x;
    const int xcd = wid & 7;
    const int j5  = wid >> 3;
    const int nsl = j5 & 7;
    const int tix = (j5 >> 3) * 8 + xcd;
    if (tix >= ws[WS_NTILES]) return;
    const int e   = ws[WS_TILE_E + tix];
    const int m0  = ws[WS_TILE_M + tix];
    const int s0  = ws[WS_STARTS + e];
    const int cnt = ws[WS_STARTS + e + 1] - s0;
    const int n0  = nsl * TN5;

    __shared__ short Ahi[2][8 * 512];   // [buf][tile(8)][slot(64)][8]
    __shared__ short Alo[2][8 * 512];
    __shared__ short Bhi[2][8 * 512];
    __shared__ short Blo[2][8 * 512];
    __shared__ int   rows_s[TM5];

    const int t = threadIdx.x;
    if (t < TM5) {
        const int r = m0 + t;
        rows_s[t] = (r < cnt) ? ws[WS_PERM + s0 + r] : -1;
    }
    __syncthreads();

    const int lane = t & 63;
    const int wave = t >> 6;          // 0..7
    const int wm = (wave >> 1) * 32;  // quadrant m base (0,32,64,96)
    const int wn = (wave & 1) * 64;   // quadrant n base (0,64)

    const float zf = 0.f;
    f32x4 acc[2][4];
#pragma unroll
    for (int mi = 0; mi < 2; ++mi)
#pragma unroll
        for (int nj = 0; nj < 4; ++nj)
            acc[mi][nj] = (f32x4){zf, zf, zf, zf};

    // A staging: wave w stages frag tile w (rows w*16..w*16+15); lane l ->
    // row w*16+(l&15), k-octet (l>>4). Clamped row for pads (uniform vmcnt);
    // pad-row acc is garbage but never stored.
    const int arow0 = rows_s[wave * 16 + (lane & 15)];
    const int arow  = arow0 < 0 ? 0 : arow0;
    const short* aSrcHi = Xhi + (size_t)arow * D_IN + (lane >> 4) * 8;
    const short* aSrcLo = Xlo + (size_t)arow * D_IN + (lane >> 4) * 8;

    // B staging: staged block ((e*32+kt)*8+nsl)*4096 shorts; wave w stages
    // frag tile w (contiguous 1KB).
    const size_t wBase = ((size_t)e * 256 + (size_t)nsl) * 4096;
    const size_t bo = (size_t)wave * 512 + lane * 8;

#define STAGE(KT, BUF) do {                                                    \
        const int _kt = (KT);                                                  \
        __builtin_amdgcn_global_load_lds(                                      \
            (const __attribute__((address_space(1))) void*)(aSrcHi + _kt * 32),\
            (__attribute__((address_space(3))) void*)&Ahi[BUF][wave * 512],    \
            16, 0, 0);                                                         \
        __builtin_amdgcn_global_load_lds(                                      \
            (const __attribute__((address_space(1))) void*)(aSrcLo + _kt * 32),\
            (__attribute__((address_space(3))) void*)&Alo[BUF][wave * 512],    \
            16, 0, 0);                                                         \
        {                                                                      \
            const size_t _wo = wBase + (size_t)_kt * 32768;                    \
            __builtin_amdgcn_global_load_lds(                                  \
                (const __attribute__((address_space(1))) void*)(Whi + _wo + bo), \
                (__attribute__((address_space(3))) void*)&Bhi[BUF][wave * 512],\
                16, 0, 0);                                                     \
            __builtin_amdgcn_global_load_lds(                                  \
                (const __attribute__((address_space(1))) void*)(Wlo + _wo + bo), \
                (__attribute__((address_space(3))) void*)&Blo[BUF][wave * 512],\
                16, 0, 0);                                                     \
        }                                                                      \
    } while (0)

    const int rds = lane * 8;   // linear fragment read, conflict-free

#define FRAG_MFMA(BUF) do {                                                  \
        short8 ah[2], al[2], bh[4], bl[4];                                   \
        _Pragma("unroll")                                                    \
        for (int i2 = 0; i2 < 2; ++i2) {                                     \
            const int aoff = ((wm >> 4) + i2) * 512 + rds;                   \
            ah[i2] = *(const short8*)&Ahi[BUF][aoff];                        \
            al[i2] = *(const short8*)&Alo[BUF][aoff];                        \
        }                                                                    \
        _Pragma("unroll")                                                    \
        for (int i2 = 0; i2 < 4; ++i2) {                                     \
            const int boff = ((wn >> 4) + i2) * 512 + rds;                   \
            bh[i2] = *(const short8*)&Bhi[BUF][boff];                        \
            bl[i2] = *(const short8*)&Blo[BUF][boff];                        \
        }                                                                    \
        _Pragma("unroll")                                                    \
        for (int mi = 0; mi < 2; ++mi)                                       \
            _Pragma("unroll")                                                \
            for (int nj = 0; nj < 4; ++nj) {                                 \
                acc[mi][nj] = __builtin_amdgcn_mfma_f32_16x16x32_bf16(ah[mi], bh[nj], acc[mi][nj], 0, 0, 0); \
                acc[mi][nj] = __builtin_amdgcn_mfma_f32_16x16x32_bf16(ah[mi], bl[nj], acc[mi][nj], 0, 0, 0); \
                acc[mi][nj] = __builtin_amdgcn_mfma_f32_16x16x32_bf16(al[mi], bh[nj], acc[mi][nj], 0, 0, 0); \
            }                                                                \
    } while (0)

#define WAIT4_BAR() asm volatile("s_waitcnt vmcnt(4)\n\ts_barrier" ::: "memory")
#define WAIT0_BAR() asm volatile("s_waitcnt vmcnt(0)\n\ts_barrier" ::: "memory")
#define READ_FENCE() asm volatile("s_waitcnt lgkmcnt(0)\n\ts_barrier" ::: "memory")

    // prologue: stage tiles 0,1 -> 8 outstanding per wave
    STAGE(0, 0);
    STAGE(1, 1);

    int kt = 2;
#pragma unroll 1
    for (int i = 0; i < 15; ++i) {
        WAIT4_BAR();          // S(2i) done; S(2i+1) in flight
        FRAG_MFMA(0);
        READ_FENCE();
        STAGE(kt, 0);         // tile 2i+2
        WAIT4_BAR();          // S(2i+1) done; S(2i+2) in flight
        FRAG_MFMA(1);
        READ_FENCE();
        STAGE(kt + 1, 1);     // tile 2i+3
        kt += 2;
    }
    WAIT4_BAR();              // S(30) done; S(31) in flight
    FRAG_MFMA(0);
    WAIT0_BAR();              // S(31) done
    FRAG_MFMA(1);

#undef STAGE
#undef FRAG_MFMA
#undef WAIT4_BAR
#undef WAIT0_BAR
#undef READ_FENCE

    // Epilogue: C/D layout col=lane&15, row=(lane>>4)*4+reg
    const int cl = lane & 15;
    const int qd = lane >> 4;
    float bv[4];
#pragma unroll
    for (int nj = 0; nj < 4; ++nj)
        bv[nj] = bias[e * D_OUT + n0 + wn + nj * 16 + cl];
#pragma unroll
    for (int mi = 0; mi < 2; ++mi) {
#pragma unroll
        for (int reg = 0; reg < 4; ++reg) {
            const int mloc = wm + mi * 16 + qd * 4 + reg;
            const int r = rows_s[mloc];
            if (r >= 0) {
                float* orow = out + (size_t)r * D_OUT + n0 + wn + cl;
#pragma unroll
                for (int nj = 0; nj < 4; ++nj)
                    orow[nj * 16] = acc[mi][nj][reg] + bv[nj];
            }
        }
    }
}

// ---------------------------------------------------------------------------
// Fallback GEMM (R2, validated; TM=64 tile list): used if ws too small.
// ---------------------------------------------------------------------------
#define TMF 64
#define TNF 128

__global__ __launch_bounds__(256) void moe_gemm_fb(
    const float* __restrict__ xs, const float* __restrict__ W,
    const float* __restrict__ bias, const int* __restrict__ ws,
    float* __restrict__ out)
{
    const int tix = blockIdx.y;
    if (tix >= ws[WS_NTILES]) return;
    const int e   = ws[WS_TILE_E + tix];
    const int m0  = ws[WS_TILE_M + tix];
    const int s0  = ws[WS_STARTS + e];
    const int cnt = ws[WS_STARTS + e + 1] - s0;
    const int n0  = blockIdx.x * TNF;

    __shared__ short Ahi[2][TMF * TK];
    __shared__ short Alo[2][TMF * TK];
    __shared__ short Bhi[2][TNF * TK];
    __shared__ short Blo[2][TNF * TK];
    __shared__ int   rows_s[TMF];

    const int t = threadIdx.x;
    if (t < TMF) {
        const int r = m0 + t;
        rows_s[t] = (r < cnt) ? ws[WS_PERM + s0 + r] : -1;
    }
    __syncthreads();

    const int lane = t & 63;
    const int wave = t >> 6;
    const int wm = (wave & 1) * 32;
    const int wn = (wave >> 1) * 64;

    const float zf = 0.f;
    f32x4 acc[2][4];
#pragma unroll
    for (int mi = 0; mi < 2; ++mi)
#pragma unroll
        for (int nj = 0; nj < 4; ++nj)
            acc[mi][nj] = (f32x4){zf, zf, zf, zf};

    const float* Wb = W + (size_t)e * (D_OUT * (size_t)D_IN) + (size_t)n0 * D_IN;

    const int j  = t & 3;
    const int rr = t >> 2;

    const int arow = rows_s[rr];
    const float* aptr = (arow >= 0) ? (xs + (size_t)arow * D_IN + j * 8) : nullptr;

    const int slotA   = (j * 16 + (rr & 15)) ^ (j << 1);
    const int aoff_st = (rr >> 4) * 512 + slotA * 8;
    const int boff0   = aoff_st;
    const int boff1   = aoff_st + 4 * 512;

    const float* qb0 = Wb + (size_t)rr * D_IN + j * 8;
    const float* qb1 = Wb + (size_t)(64 + rr) * D_IN + j * 8;

    const int rds = (lane ^ ((lane >> 4) << 1)) * 8;

#define LOAD_SET(A0, A1, B0, B1, B2, B3, KOFF) do {                          \
        const int _k = (KOFF);                                               \
        if (aptr) {                                                          \
            A0 = *(const float4*)(aptr + _k);                                \
            A1 = *(const float4*)(aptr + _k + 4);                            \
        }                                                                    \
        B0 = *(const float4*)(qb0 + _k); B1 = *(const float4*)(qb0 + _k + 4);\
        B2 = *(const float4*)(qb1 + _k); B3 = *(const float4*)(qb1 + _k + 4);\
    } while (0)

#define CVT_STORE_SET(A0, A1, B0, B1, B2, B3, BUF) do {                      \
        short8 _h, _l;                                                       \
        cvt8(A0, A1, _h, _l);                                                \
        *(short8*)&Ahi[BUF][aoff_st] = _h; *(short8*)&Alo[BUF][aoff_st] = _l;\
        cvt8(B0, B1, _h, _l);                                                \
        *(short8*)&Bhi[BUF][boff0] = _h;   *(short8*)&Blo[BUF][boff0] = _l;  \
        cvt8(B2, B3, _h, _l);                                                \
        *(short8*)&Bhi[BUF][boff1] = _h;   *(short8*)&Blo[BUF][boff1] = _l;  \
    } while (0)

#define FRAG_MFMA(BUF) do {                                                  \
        short8 ah[2], al[2], bh[4], bl[4];                                   \
        _Pragma("unroll")                                                    \
        for (int i2 = 0; i2 < 2; ++i2) {                                     \
            const int aoff = ((wm >> 4) + i2) * 512 + rds;                   \
            ah[i2] = *(const short8*)&Ahi[BUF][aoff];                        \
            al[i2] = *(const short8*)&Alo[BUF][aoff];                        \
        }                                                                    \
        _Pragma("unroll")                                                    \
        for (int i2 = 0; i2 < 4; ++i2) {                                     \
            const int boff = ((wn >> 4) + i2) * 512 + rds;                   \
            bh[i2] = *(const short8*)&Bhi[BUF][boff];                        \
            bl[i2] = *(const short8*)&Blo[BUF][boff];                        \
        }                                                                    \
        _Pragma("unroll")                                                    \
        for (int mi = 0; mi < 2; ++mi)                                       \
            _Pragma("unroll")                                                \
            for (int nj = 0; nj < 4; ++nj) {                                 \
                acc[mi][nj] = __builtin_amdgcn_mfma_f32_16x16x32_bf16(ah[mi], bh[nj], acc[mi][nj], 0, 0, 0); \
                acc[mi][nj] = __builtin_amdgcn_mfma_f32_16x16x32_bf16(ah[mi], bl[nj], acc[mi][nj], 0, 0, 0); \
                acc[mi][nj] = __builtin_amdgcn_mfma_f32_16x16x32_bf16(al[mi], bh[nj], acc[mi][nj], 0, 0, 0); \
            }                                                                \
    } while (0)

#define PIPE_BARRIER() asm volatile("s_waitcnt lgkmcnt(0)\n\ts_barrier" ::: "memory")

    float4 ax0 = make_float4(0.f, 0.f, 0.f, 0.f), ax1 = ax0;
    float4 bx0, bx1, bx2, bx3;
    float4 ay0 = make_float4(0.f, 0.f, 0.f, 0.f), ay1 = ay0;
    float4 by0, by1, by2, by3;

    LOAD_SET(ax0, ax1, bx0, bx1, bx2, bx3, 0);
    CVT_STORE_SET(ax0, ax1, bx0, bx1, bx2, bx3, 0);
    LOAD_SET(ax0, ax1, bx0, bx1, bx2, bx3, TK);
    PIPE_BARRIER();

    int ke = 2 * TK;
#pragma unroll 1
    for (int i = 0; i < 15; ++i) {
        {
            LOAD_SET(ay0, ay1, by0, by1, by2, by3, ke);
            FRAG_MFMA(0);
            CVT_STORE_SET(ax0, ax1, bx0, bx1, bx2, bx3, 1);
            PIPE_BARRIER();
        }
        {
            LOAD_SET(ax0, ax1, bx0, bx1, bx2, bx3, ke + TK);
            FRAG_MFMA(1);
            CVT_STORE_SET(ay0, ay1, by0, by1, by2, by3, 0);
            PIPE_BARRIER();
        }
        ke += 2 * TK;
    }
    {
        FRAG_MFMA(0);
        CVT_STORE_SET(ax0, ax1, bx0, bx1, bx2, bx3, 1);
        PIPE_BARRIER();
    }
    {
        FRAG_MFMA(1);
    }

#undef LOAD_SET
#undef CVT_STORE_SET
#undef FRAG_MFMA
#undef PIPE_BARRIER

    const int cl = lane & 15;
    const int qd = lane >> 4;
    float bv[4];
#pragma unroll
    for (int nj = 0; nj < 4; ++nj)
        bv[nj] = bias[e * D_OUT + n0 + wn + nj * 16 + cl];
#pragma unroll
    for (int mi = 0; mi < 2; ++mi) {
#pragma unroll
        for (int reg = 0; reg < 4; ++reg) {
            const int mloc = wm + mi * 16 + qd * 4 + reg;
            const int r = rows_s[mloc];
            if (r >= 0) {
                float* orow = out + (size_t)r * D_OUT + n0 + wn + cl;
#pragma unroll
                for (int nj = 0; nj < 4; ++nj)
                    orow[nj * 16] = acc[mi][nj][reg] + bv[nj];
            }
        }
    }
}

extern "C" void kernel_launch(void* const* d_in, const int* in_sizes, int n_in,
                              void* d_out, int out_size, void* d_ws, size_t ws_size,
                              hipStream_t stream) {
    const float* xs      = (const float*)d_in[0];
    const int*   mxs     = (const int*)d_in[1];
    const int*   actions = (const int*)d_in[2];
    const float* W       = (const float*)d_in[3];
    const float* bias    = (const float*)d_in[4];
    float* out = (float*)d_out;
    int*   ws  = (int*)d_ws;
    char*  wsb = (char*)d_ws;

    short* XhiP = (short*)(wsb + WS_XHI_OFF);
    short* XloP = (short*)(wsb + WS_XLO_OFF);
    short* WhiP = (short*)(wsb + WS_WHI_OFF);
    short* WloP = (short*)(wsb + WS_WLO_OFF);

    const int metaOff = BATCH * D_OUT;
    const int meta_mode = (out_size >= metaOff + 3 * BATCH) ? 2
                        : (out_size >= metaOff + 2 * BATCH) ? 1 : 0;

    const bool big = ws_size >= (size_t)WS_NEEDED;
    const int prep_blocks = big ? (17 + 6144) : 17;
    const int tm_tile = big ? TM5 : TMF;

    prep_kernel<<<prep_blocks, 256, 0, stream>>>(
        actions, mxs, xs, W, ws, XhiP, XloP, WhiP, WloP, out, meta_mode, tm_tile);

    if (big) {
        // grid 8*(MAX_TILES_128+1): j in [0,40) so (tix/8)=4 covers nsl=7
        moe_gemm_pc<<<8 * (MAX_TILES_128 + 1), 512, 0, stream>>>(
            XhiP, XloP, WhiP, WloP, bias, ws, out);
    } else {
        dim3 grid(D_OUT / TNF, MAX_TILES, 1);
        moe_gemm_fb<<<grid, 256, 0, stream>>>(xs, W, bias, ws, out);
    }
}